// Round 4
// baseline (218.212 us; speedup 1.0000x reference)
//
#include <hip/hip_runtime.h>
#include <utility>
#include <cstddef>

#define NT     111
#define LMAX   5
#define TAU    32
#define NBATCH 32
#define ROW    2304   // f32 elements per batch row of fs

struct Tup { int l, l1, l2, out_off, in1, in2, cg_off; };
struct Meta { Tup t[NT]; int totch, totcg; };

constexpr int IN_OFF[LMAX + 1] = {0, 64, 256, 576, 1024, 1600};

constexpr Meta make_meta() {
  Meta m{};
  int n = 0, out = 0, cg = 0;
  for (int l = 0; l <= LMAX; ++l)
    for (int l1 = 0; l1 <= LMAX; ++l1)
      for (int l2 = 0; l2 <= LMAX; ++l2) {
        int df = l1 - l2; if (df < 0) df = -df;
        if (df <= l && l <= l1 + l2) {
          m.t[n] = Tup{l, l1, l2, out, IN_OFF[l1], IN_OFF[l2], cg};
          out += TAU * TAU * (2 * l + 1);
          cg  += (2 * l + 1) * (2 * l1 + 1);   // compact [D][D1] table
          ++n;
        }
      }
  m.totch = out; m.totcg = cg;
  return m;
}

constexpr Meta META  = make_meta();
constexpr int  TOTCH = META.totch;   // 789504 complex pairs per batch
constexpr int  TOTCG = META.totcg;   // 5515 floats (22 KB)

// ---------- compile-time CG coefficients ----------
constexpr double cfact(int n) { double r = 1.0; for (int i = 2; i <= n; ++i) r *= i; return r; }

constexpr double csqrt(double x) {
  if (x <= 0.0) return 0.0;
  double g = x;
  for (int i = 0; i < 100; ++i) g = 0.5 * (g + x / g);  // Newton, converges to f64 ulp
  return g;
}

// Condon-Shortley CG coefficient <j1 m1 j2 m2 | j3 m3>, Racah formula, f64 exact factorials.
constexpr double cg_coef_ct(int j1, int m1, int j2, int m2, int j3, int m3) {
  if (m1 + m2 != m3) return 0.0;
  double pref = csqrt((2.0 * j3 + 1.0) * cfact(j3 + j1 - j2) * cfact(j3 - j1 + j2) *
                      cfact(j1 + j2 - j3) / cfact(j1 + j2 + j3 + 1));
  pref *= csqrt(cfact(j3 + m3) * cfact(j3 - m3) * cfact(j1 - m1) * cfact(j1 + m1) *
                cfact(j2 - m2) * cfact(j2 + m2));
  double s = 0.0;
  const int kmax = j1 + j2 - j3;
  for (int k = 0; k <= kmax; ++k) {
    const int a3 = j1 - m1 - k, a4 = j2 + m2 - k, a5 = j3 - j2 + m1 + k, a6 = j3 - j1 - m2 + k;
    if (a3 < 0 || a4 < 0 || a5 < 0 || a6 < 0) continue;
    const double den = cfact(k) * cfact(kmax - k) * cfact(a3) * cfact(a4) * cfact(a5) * cfact(a6);
    s += ((k & 1) ? -1.0 : 1.0) / den;
  }
  return pref * s;
}

// Per-tuple compact table [D][D1]: CG value at the unique valid i2 for (m,i1),
// 0 where i2 out of range. Separate constexpr variable per tuple keeps each
// evaluation well under clang's per-initializer step limit.
template<int I>
struct CGC {
  static constexpr int L  = META.t[I].l, L1 = META.t[I].l1, L2 = META.t[I].l2;
  static constexpr int D = 2 * L + 1, D1 = 2 * L1 + 1, D2 = 2 * L2 + 1;
  struct T { float v[D * D1]; };
  static constexpr T gen() {
    T t{};
    for (int m = 0; m < D; ++m)
      for (int i1 = 0; i1 < D1; ++i1) {
        const int i2 = (m - L) - (i1 - L1) + L2;
        t.v[m * D1 + i1] = (i2 >= 0 && i2 < D2)
            ? (float)cg_coef_ct(L1, i1 - L1, L2, i2 - L2, L, m - L) : 0.0f;
      }
    return t;
  }
  static constexpr T tab = gen();
};

struct Flat { float v[TOTCG]; };

template<int I>
constexpr void copy_one(Flat& f) {
  constexpr int n = (2 * META.t[I].l + 1) * (2 * META.t[I].l1 + 1);
  for (int k = 0; k < n; ++k) f.v[META.t[I].cg_off + k] = CGC<I>::tab.v[k];
}
template<std::size_t... Is>
constexpr Flat build_flat(std::index_sequence<Is...>) {
  Flat f{};
  (copy_one<(int)Is>(f), ...);
  return f;
}
constexpr Flat CG_FLAT_H = build_flat(std::make_index_sequence<NT>{});

// device-side copies (constant-initialized, live in .rodata of the code object)
__device__ const Flat CG_FLAT = CG_FLAT_H;
__device__ const Meta D_META  = META;

// ---------- ONE generic body for all 111 tuples ----------
// ~400 instructions total -> permanently I$-resident for every block on every
// CU (the 111 specialized bodies were ~300 KB of code; round-2/-3 evidence
// says instruction fetch was the dominant stall). CG coefficients come from a
// per-block LDS table (uniform broadcast reads); a/b fragments live in small
// LDS tiles so all inner-loop indexing is runtime without register spills.
// All loop bounds are wave-uniform -> scalar branches, zero divergence.
__global__ void __launch_bounds__(256)
cg_main(const float* __restrict__ fs, float2* __restrict__ out) {
  __shared__ float  s_re[256 * 11];   // result staging, [pair-in-tile][m] flat
  __shared__ float  s_im[256 * 11];
  __shared__ float2 s_b[32 * 11];     // b-fragments, [t2][i2]
  __shared__ float2 s_a[8 * 11];      // a-fragments for current j, [t1l][i1]
  __shared__ float  s_cg[121];        // compact CG table [m][i1]

  const int tid = threadIdx.x;
  const Tup tp  = D_META.t[blockIdx.x];          // wave-uniform scalar loads
  const int L = tp.l, L1 = tp.l1, L2 = tp.l2;
  const int D = 2 * L + 1, D1 = 2 * L1 + 1, D2 = 2 * L2 + 1;
  const int b = blockIdx.y;

  const float2* fa = (const float2*)(fs + b * ROW + tp.in1);
  const float2* fb = (const float2*)(fs + b * ROW + tp.in2);
  float2* po = out + (size_t)b * TOTCH + tp.out_off;

  // stage CG table and all 32 b-fragment rows once per block
  for (int i = tid; i < D * D1; i += 256) s_cg[i] = CG_FLAT.v[tp.cg_off + i];
  {
    const int r = tid & 31;                       // t2 row
    for (int c = tid >> 5; c < D2; c += 8) s_b[r * D2 + c] = fb[r * D2 + c];
  }

  const int t1l  = tid >> 5;   // 0..7: local a-row for this j
  const int t2   = tid & 31;
  const int resb = tid * D;

  for (int j = 0; j < 4; ++j) {
    // stage this j's 8 a-rows (global t1 = 8j + t1l); one float2 per thread
    if ((tid >> 3) < D1)
      s_a[(tid & 7) * D1 + (tid >> 3)] = fa[(8 * j + (tid & 7)) * D1 + (tid >> 3)];
    __syncthreads();  // s_a (and, at j=0, s_b/s_cg) visible; prev store phase done

    const float2* pa = s_a + t1l * D1;
    const float2* pb = s_b + t2 * D2;
    const float*  cgrow = s_cg;
    for (int m = 0; m < D; ++m, cgrow += D1) {
      const int S = m - L + L1 + L2;              // i2 = S - i1
      int lo = S - (D2 - 1); if (lo < 0) lo = 0;
      int hi = S;            if (hi > D1 - 1) hi = D1 - 1;
      float re = 0.f, im = 0.f;
      for (int i1 = lo; i1 <= hi; ++i1) {
        const float  c  = cgrow[i1];              // uniform broadcast
        const float2 a  = pa[i1];                 // broadcast within 32-lane group
        const float2 bb = pb[S - i1];
        re += c * (a.x * bb.x - a.y * bb.y);
        im += c * (a.x * bb.y + a.y * bb.x);
      }
      s_re[resb + m] = re;                        // stride D odd -> conflict-free
      s_im[resb + m] = im;
    }
    __syncthreads();  // results staged

    // stream the contiguous 256*D*8B j-tile out as coalesced float4
    float4* oj4 = (float4*)(po + (size_t)(256 * j) * D);
    const int NV = 128 * D;
    for (int e = tid; e < NV; e += 256)
      oj4[e] = make_float4(s_re[2 * e], s_im[2 * e],
                           s_re[2 * e + 1], s_im[2 * e + 1]);
  }
}

extern "C" void kernel_launch(void* const* d_in, const int* in_sizes, int n_in,
                              void* d_out, int out_size, void* d_ws, size_t ws_size,
                              hipStream_t stream) {
  const float* fs = (const float*)d_in[0];
  float2* out = (float2*)d_out;
  (void)d_ws; (void)ws_size; (void)in_sizes; (void)n_in; (void)out_size;

  // grid back to round-2 order: x = tuple (consecutive blocks write
  // contiguous output regions -> L2 write locality), y = batch
  cg_main<<<dim3(NT, NBATCH), dim3(256), 0, stream>>>(fs, out);
}

// Round 5
// 198.651 us; speedup vs baseline: 1.0985x; 1.0985x over previous
//
#include <hip/hip_runtime.h>

#define NT     111
#define LMAX   5
#define TAU    32
#define NBATCH 32
#define ROW    2304   // f32 elements per batch row of fs

struct Tup { int l, l1, l2, out_off, in1, in2; };
struct Meta { Tup t[NT]; int totch; };

constexpr int IN_OFF[LMAX + 1] = {0, 64, 256, 576, 1024, 1600};

constexpr Meta make_meta() {
  Meta m{};
  int n = 0, out = 0;
  for (int l = 0; l <= LMAX; ++l)
    for (int l1 = 0; l1 <= LMAX; ++l1)
      for (int l2 = 0; l2 <= LMAX; ++l2) {
        int df = l1 - l2; if (df < 0) df = -df;
        if (df <= l && l <= l1 + l2) {
          m.t[n].l = l; m.t[n].l1 = l1; m.t[n].l2 = l2;
          m.t[n].out_off = out;
          m.t[n].in1 = IN_OFF[l1]; m.t[n].in2 = IN_OFF[l2];
          out += TAU * TAU * (2 * l + 1);
          ++n;
        }
      }
  m.totch = out;
  return m;
}

constexpr Meta META  = make_meta();
constexpr int  TOTCH = META.totch;   // 789504 complex pairs per batch

// ---------- compile-time CG coefficients ----------
constexpr double cfact(int n) { double r = 1.0; for (int i = 2; i <= n; ++i) r *= i; return r; }

constexpr double csqrt(double x) {
  if (x <= 0.0) return 0.0;
  double g = x;
  for (int i = 0; i < 100; ++i) g = 0.5 * (g + x / g);  // Newton, converges to f64 ulp
  return g;
}

// Condon-Shortley CG coefficient <j1 m1 j2 m2 | j3 m3>, Racah formula, f64 exact factorials.
constexpr double cg_coef_ct(int j1, int m1, int j2, int m2, int j3, int m3) {
  if (m1 + m2 != m3) return 0.0;
  double pref = csqrt((2.0 * j3 + 1.0) * cfact(j3 + j1 - j2) * cfact(j3 - j1 + j2) *
                      cfact(j1 + j2 - j3) / cfact(j1 + j2 + j3 + 1));
  pref *= csqrt(cfact(j3 + m3) * cfact(j3 - m3) * cfact(j1 - m1) * cfact(j1 + m1) *
                cfact(j2 - m2) * cfact(j2 + m2));
  double s = 0.0;
  const int kmax = j1 + j2 - j3;
  for (int k = 0; k <= kmax; ++k) {
    const int a3 = j1 - m1 - k, a4 = j2 + m2 - k, a5 = j3 - j2 + m1 + k, a6 = j3 - j1 - m2 + k;
    if (a3 < 0 || a4 < 0 || a5 < 0 || a6 < 0) continue;
    const double den = cfact(k) * cfact(kmax - k) * cfact(a3) * cfact(a4) * cfact(a5) * cfact(a6);
    s += ((k & 1) ? -1.0 : 1.0) / den;
  }
  return pref * s;
}

// Per-tuple constexpr table (separate variable per tuple keeps each constexpr
// evaluation ~100k steps, under clang's per-initializer limit).
template<int L, int L1, int L2>
struct CGTab {
  struct T { float v[2 * L + 1][2 * L1 + 1][2 * L2 + 1]; };
  static constexpr T gen() {
    T t{};
    for (int m = 0; m < 2 * L + 1; ++m)
      for (int i1 = 0; i1 < 2 * L1 + 1; ++i1)
        for (int i2 = 0; i2 < 2 * L2 + 1; ++i2)
          t.v[m][i1][i2] = (float)cg_coef_ct(L1, i1 - L1, L2, i2 - L2, L, m - L);
    return t;
  }
  static constexpr T tab = gen();
};

// ---------- per-tuple contraction ----------
// Thread t owns (t1,t2) pairs tp = t + 256*j, j=0..3; t2 = t&31 is j-invariant.
// m/i1 loops unroll to straight-line FMAs with CG values as immediates.
// j-loop NOT unrolled (#pragma unroll 1): keeps per-body code ~3 KB so the
// ~7 co-resident blocks' bodies fit the 32 KB I$ (round-2 evidence: -28 us).
//
// Store path (round-5 change): the transpose is WAVE-PRIVATE. A wave's 64
// pairs form one contiguous 64*D output tile, so each wave stages res[] into
// its own LDS slice and reads it back transposed -- ordering needs only
// same-wave s_waitcnt lgkmcnt(0) (DS ops are wave-in-order), NOT
// __syncthreads. Zero barriers => no per-j vmcnt(0) store drain; compute and
// the store stream of all 28 waves/CU pipeline freely. Stores are
// ds_read_b128 + global_store_dwordx4 (16 B/lane, conflict-free).
template<int L, int L1, int L2>
__device__ __forceinline__ void tuple_impl(const float* __restrict__ fa,
                                           const float* __restrict__ fb,
                                           float2* __restrict__ po,
                                           float2* __restrict__ stage) {
  constexpr int D = 2 * L + 1, D1 = 2 * L1 + 1, D2 = 2 * L2 + 1;
  const int tid  = threadIdx.x;
  const int lane = tid & 63;
  const int wv   = tid >> 6;
  float2* swave = stage + wv * (64 * D);   // this wave's private slice

  const int t2 = tid & 31;
  float br[D2], bi[D2];
  const float2* pb = (const float2*)fb + t2 * D2;
  #pragma unroll
  for (int i = 0; i < D2; ++i) { float2 v = pb[i]; br[i] = v.x; bi[i] = v.y; }

  #pragma unroll 1
  for (int j = 0; j < 4; ++j) {
    const int tp = tid + 256 * j;
    const int t1 = tp >> 5;

    float ar[D1], ai[D1];
    const float2* pa = (const float2*)fa + t1 * D1;
    #pragma unroll
    for (int i = 0; i < D1; ++i) { float2 v = pa[i]; ar[i] = v.x; ai[i] = v.y; }

    float2 res[D];
    #pragma unroll
    for (int m = 0; m < D; ++m) {
      float re = 0.f, im = 0.f;
      #pragma unroll
      for (int i1 = 0; i1 < D1; ++i1) {
        const int i2 = (m - L) - (i1 - L1) + L2;   // unroll-time constant
        if (i2 >= 0 && i2 < D2) {                   // folds after unrolling
          const float c = CGTab<L, L1, L2>::tab.v[m][i1][i2];  // immediate
          if (c != 0.f) {
            re += c * (ar[i1] * br[i2] - ai[i1] * bi[i2]);
            im += c * (ar[i1] * bi[i2] + ai[i1] * br[i2]);
          }
        }
      }
      res[m] = make_float2(re, im);
    }

    if constexpr (D == 1) {
      // natural store is already 8B/lane contiguous — no staging needed
      po[tp] = res[0];
    } else {
      // WAR fence: previous j's ds_reads complete before overwrite
      // (counter is already ~0 here; cost ~nothing)
      asm volatile("s_waitcnt lgkmcnt(0)" ::: "memory");
      #pragma unroll
      for (int m = 0; m < D; ++m) swave[lane * D + m] = res[m];
      // RAW fence: writes complete before transposed reads
      asm volatile("s_waitcnt lgkmcnt(0)" ::: "memory");

      // wave tile = pairs [256j + 64wv, +64) x D, contiguous 512*D bytes
      const float4* s4  = (const float4*)swave;
      float4*       ow4 = (float4*)(po + (size_t)(256 * j + 64 * wv) * D);
      #pragma unroll
      for (int k = 0; k <= (D - 1) / 2; ++k) {        // 32*D float4 total
        const int f = lane + 64 * k;
        if (k < (D - 1) / 2 || lane < 32)             // last k: half wave
          ow4[f] = s4[f];
      }
    }
  }
}

// ---------- compile-time BINARY dispatch over the 111 tuples ----------
template<int LO, int HI>
__device__ __forceinline__ void dispatch(int idx, int b,
                                         const float* __restrict__ fs,
                                         float2* __restrict__ out,
                                         float2* __restrict__ stage) {
  if constexpr (HI - LO == 1) {
    constexpr Tup t = META.t[LO];
    tuple_impl<t.l, t.l1, t.l2>(fs + b * ROW + t.in1,
                                fs + b * ROW + t.in2,
                                out + (size_t)b * TOTCH + t.out_off,
                                stage);
  } else {
    constexpr int MID = LO + (HI - LO) / 2;
    if (idx < MID) dispatch<LO, MID>(idx, b, fs, out, stage);
    else           dispatch<MID, HI>(idx, b, fs, out, stage);
  }
}

__global__ void __launch_bounds__(256)
cg_main(const float* __restrict__ fs, float2* __restrict__ out) {
  // 4 waves x 64 pairs x D<=11 float2 = 22.5 KB -> 7 blocks/CU
  __shared__ float2 stage[4 * 64 * 11];
  dispatch<0, NT>(blockIdx.x, blockIdx.y, fs, out, stage);
}

extern "C" void kernel_launch(void* const* d_in, const int* in_sizes, int n_in,
                              void* d_out, int out_size, void* d_ws, size_t ws_size,
                              hipStream_t stream) {
  const float* fs = (const float*)d_in[0];
  float2* out = (float2*)d_out;
  (void)d_ws; (void)ws_size; (void)in_sizes; (void)n_in; (void)out_size;

  // x = tuple (consecutive blocks write contiguous output -> L2 locality)
  cg_main<<<dim3(NT, NBATCH), dim3(256), 0, stream>>>(fs, out);
}